// Round 1
// 380.042 us; speedup vs baseline: 1.0585x; 1.0585x over previous
//
#include <hip/hip_runtime.h>
#include <stdint.h>

typedef __attribute__((ext_vector_type(4))) int  int32x4;
typedef __attribute__((ext_vector_type(16))) int int32x16;

#define M_DIM 8192
#define N_DIM 4096
#define K_DIM 4096
#define KT    (K_DIM / 64)   // 64 K-tiles of 64 bytes each

// ---------------------------------------------------------------------------
// Global tile layout (unchanged, verified conflict-free in GEMM ds_reads):
//   cell(rt, kt, ks, kh, row) at byte (rt*KT + kt)*8192 + ks*4096 + kh*2048 + row*16
//   holds element (m = rt*128+row, k = kt*64 + ks*32 + kh*16 + byte), 16B/cell.
// ---------------------------------------------------------------------------

__device__ __forceinline__ int pack4(float4 f) {
  int a = ((int)f.x) & 255;
  int b = ((int)f.y) & 255;
  int c = ((int)f.z) & 255;
  int d = ((int)f.w) & 255;
  return a | (b << 8) | (c << 16) | (d << 24);
}

// ---------------------------------------------------------------------------
// Convert: fp32 -> i8 tiled.  Same structure as before, but the LDS write
// was a 16-way bank conflict (bank = row*4 + (l&3), row wave-uniform).
// Fix: XOR-swizzle row within each 512-word group: row' = row ^ (G&7),
// G = l>>2.  Write banks now cover all 32 banks 2x (free).  The streaming
// read applies the same involution; cells stay 16B-contiguous so the b128
// read remains conflict-free, and global writes remain linear.
// ---------------------------------------------------------------------------
#define BLKS_A (64 * 16)   // rtA=64, kq=16
#define BLKS_B (32 * 16)

__global__ __launch_bounds__(256) void f32_to_i8_tiled(
    const float* __restrict__ xa, const float* __restrict__ xw,
    int4* __restrict__ dstA, int4* __restrict__ dstB)
{
  __shared__ int ts[8192];   // 32 KB, u32-addressed

  int bid = blockIdx.x;
  const float* src;
  int4* dst;
  int rt, kq;
  if (bid < BLKS_A) { src = xa; dst = dstA; rt = bid >> 4; kq = bid & 15; }
  else { bid -= BLKS_A; src = xw; dst = dstB; rt = bid >> 4; kq = bid & 15; }

  const int w = threadIdx.x >> 6;      // wave 0..3
  const int l = threadIdx.x & 63;

  const int G  = l >> 2;               // group 0..15 (= t4*4 + ks*2 + kh)
  const int gs = G & 7;                // swizzle key
  const int ldsBase = (G << 9) + (l & 3);

  const float* rowp = src + (size_t)(rt * 128 + w) * K_DIM + kq * 256 + l * 4;

#pragma unroll 4
  for (int i = 0; i < 32; ++i) {
    int row = i * 4 + w;
    float4 f = *(const float4*)(rowp + (size_t)i * 4 * K_DIM);
    ts[ldsBase + ((row ^ gs) << 2)] = pack4(f);
  }
  __syncthreads();

  // Stream out 2048 cells (32 KB); un-swizzle on the read side.
  int4* outp = dst + ((size_t)rt * KT + kq * 4) * 512;
  const int4* tsv = (const int4*)ts;
#pragma unroll
  for (int kk = 0; kk < 8; ++kk) {
    int o  = threadIdx.x + kk * 256;
    int g2 = o >> 7;
    int r2 = o & 127;
    outp[o] = tsv[(g2 << 7) + (r2 ^ (g2 & 7))];
  }
}

// ---------------------------------------------------------------------------
// int8 GEMM-BT, 256x256 tile, 8 waves (2x4), per-wave 128x64 out.
// BK = 64 bytes, 3-deep LDS ring (3 x 32 KB), prefetch distance 2 K-tiles.
// Per phase (half K-tile): 6 ds_read_b128 || 2 global_load_lds(16B) ->
// lgkmcnt(0) -> counted vmcnt(6) -> raw s_barrier -> setprio(1) + 8 MFMA.
// Never vmcnt(0) in the main loop (T3+T4); tail peels vmcnt 4 -> 2 -> 0.
// ---------------------------------------------------------------------------

__device__ __forceinline__ void async16(const int8_t* g, int8_t* l) {
  __builtin_amdgcn_global_load_lds(
      (const __attribute__((address_space(1))) void*)g,
      (__attribute__((address_space(3))) void*)l,
      16, 0, 0);
}

__device__ __forceinline__ int32x16 zero16() {
  int32x16 v;
#pragma unroll
  for (int i = 0; i < 16; ++i) v[i] = 0;
  return v;
}

#define LDS_BUF 32768

__global__ __launch_bounds__(512, 2) void gemm_i8(
    const int8_t* __restrict__ A8, const int8_t* __restrict__ B8,
    const float* __restrict__ bias, float* __restrict__ C)
{
  __shared__ int8_t lds[3 * LDS_BUF];   // 96 KB ring: {A 16K, B 16K} x 3

  const int tid = threadIdx.x;
  const int w   = tid >> 6;            // wave 0..7
  const int l   = tid & 63;
  const int ln  = l & 31;
  const int hb  = l >> 5;
  const int wm  = w >> 2;              // 0..1  (M direction)
  const int wn  = w & 3;               // 0..3  (N direction)

  // XCD-aware swizzle: 512 blocks, 512 % 8 == 0 -> bijective chunked remap.
  const int fid = blockIdx.y * gridDim.x + blockIdx.x;
  const int swz = (fid & 7) * 64 + (fid >> 3);
  const int bn  = swz & 15;            // 16 n-tiles of 256
  const int bm  = swz >> 4;            // 32 m-tiles of 256

  // ---- staging: 16 chunks of 1KB per (K-tile, ks-half is 8 of them) ----
  // chunk c: mat = c>>3 (0=A,1=B), kh = (c>>2)&1, h = (c>>1)&1, q = c&1
  const int c0  = w * 2;
  const int c1  = c0 + 1;
  const int mt0 = c0 >> 3, kh0 = (c0 >> 2) & 1, h0 = (c0 >> 1) & 1, q0 = c0 & 1;
  const int mt1 = c1 >> 3, kh1 = (c1 >> 2) & 1, h1 = (c1 >> 1) & 1, q1 = c1 & 1;

  const int8_t* g0 = (mt0 ? B8 + (size_t)(bn * 2 + h0) * ((size_t)KT * 8192)
                          : A8 + (size_t)(bm * 2 + h0) * ((size_t)KT * 8192))
                     + kh0 * 2048 + q0 * 1024 + l * 16;
  const int8_t* g1 = (mt1 ? B8 + (size_t)(bn * 2 + h1) * ((size_t)KT * 8192)
                          : A8 + (size_t)(bm * 2 + h1) * ((size_t)KT * 8192))
                     + kh1 * 2048 + q1 * 1024 + l * 16;
  const int lo0 = mt0 * 16384 + kh0 * 4096 + h0 * 2048 + q0 * 1024;
  const int lo1 = mt1 * 16384 + kh1 * 4096 + h1 * 2048 + q1 * 1024;

#define STAGE(bufOff, kt_, ks_)                                         \
  { int go_ = (kt_) * 8192 + (ks_) * 4096;                              \
    int ld_ = (bufOff) + (ks_) * 8192;                                  \
    async16(g0 + go_, lds + ld_ + lo0);                                 \
    async16(g1 + go_, lds + ld_ + lo1); }

  // ---- fragment read offsets (conflict-free b128, same pattern as before) --
  const int aoff = hb * 4096 + (wm * 128 + ln) * 16;           // A rows 0..255
  const int boff = 16384 + hb * 4096 + (wn * 64 + ln) * 16;    // B rows 0..255

  int32x16 acc00 = zero16(), acc01 = zero16();
  int32x16 acc10 = zero16(), acc11 = zero16();
  int32x16 acc20 = zero16(), acc21 = zero16();
  int32x16 acc30 = zero16(), acc31 = zero16();

#define PHASE(off_, ks_, STG, VMW)                                           \
  { const int8_t* pb = lds + (off_) + (ks_) * 8192;                          \
    int32x4 a0 = *(const int32x4*)(pb + aoff);                               \
    int32x4 a1 = *(const int32x4*)(pb + aoff + 512);                         \
    int32x4 a2 = *(const int32x4*)(pb + aoff + 1024);                        \
    int32x4 a3 = *(const int32x4*)(pb + aoff + 1536);                        \
    int32x4 b0 = *(const int32x4*)(pb + boff);                               \
    int32x4 b1 = *(const int32x4*)(pb + boff + 512);                         \
    STG;                                                                     \
    asm volatile("s_waitcnt lgkmcnt(0)" ::: "memory");                       \
    VMW;                                                                     \
    __builtin_amdgcn_s_barrier();                                            \
    asm volatile("" ::: "memory");                                           \
    __builtin_amdgcn_s_setprio(1);                                           \
    acc00 = __builtin_amdgcn_mfma_i32_32x32x32_i8(a0, b0, acc00, 0, 0, 0);   \
    acc01 = __builtin_amdgcn_mfma_i32_32x32x32_i8(a0, b1, acc01, 0, 0, 0);   \
    acc10 = __builtin_amdgcn_mfma_i32_32x32x32_i8(a1, b0, acc10, 0, 0, 0);   \
    acc11 = __builtin_amdgcn_mfma_i32_32x32x32_i8(a1, b1, acc11, 0, 0, 0);   \
    acc20 = __builtin_amdgcn_mfma_i32_32x32x32_i8(a2, b0, acc20, 0, 0, 0);   \
    acc21 = __builtin_amdgcn_mfma_i32_32x32x32_i8(a2, b1, acc21, 0, 0, 0);   \
    acc30 = __builtin_amdgcn_mfma_i32_32x32x32_i8(a3, b0, acc30, 0, 0, 0);   \
    acc31 = __builtin_amdgcn_mfma_i32_32x32x32_i8(a3, b1, acc31, 0, 0, 0);   \
    __builtin_amdgcn_s_setprio(0); }

  // ---- prologue: stage kt=0 -> buf0, kt=1 -> buf1 (8 calls in flight) ----
  STAGE(0, 0, 0); STAGE(0, 0, 1);
  STAGE(LDS_BUF, 1, 0); STAGE(LDS_BUF, 1, 1);
  asm volatile("s_waitcnt vmcnt(6)" ::: "memory");   // (0,ks0) landed
  __builtin_amdgcn_s_barrier();
  asm volatile("" ::: "memory");

  // ---- main loop: compute kt from buf cur, prefetch kt+2 into buf cur+2 ---
  int curOff = 0;
  for (int kt = 0; kt < KT - 2; ++kt) {
    int nxtOff = curOff + 2 * LDS_BUF;
    if (nxtOff >= 3 * LDS_BUF) nxtOff -= 3 * LDS_BUF;
    PHASE(curOff, 0, STAGE(nxtOff, kt + 2, 0),
          asm volatile("s_waitcnt vmcnt(6)" ::: "memory"));
    PHASE(curOff, 1, STAGE(nxtOff, kt + 2, 1),
          asm volatile("s_waitcnt vmcnt(6)" ::: "memory"));
    curOff += LDS_BUF;
    if (curOff == 3 * LDS_BUF) curOff = 0;
  }
  // ---- tail kt = KT-2: nothing left to stage; drain 4 -> 2 ----
  PHASE(curOff, 0, (void)0, asm volatile("s_waitcnt vmcnt(4)" ::: "memory"));
  PHASE(curOff, 1, (void)0, asm volatile("s_waitcnt vmcnt(2)" ::: "memory"));
  curOff += LDS_BUF;
  if (curOff == 3 * LDS_BUF) curOff = 0;
  // ---- tail kt = KT-1: final drain ----
  PHASE(curOff, 0, (void)0, asm volatile("s_waitcnt vmcnt(0)" ::: "memory"));
  PHASE(curOff, 1, (void)0, (void)0);

  // ---- epilogue: C/D layout (32x32): col = lane&31, row = (r&3)+8*(r>>2)+4*hb
  const int colBase = bn * 256 + wn * 64 + ln;
  const int rowBase = bm * 256 + wm * 128;
  const int bias0 = (int)bias[colBase];
  const int bias1 = (int)bias[colBase + 32];

#define CWRITE(accL, accR, ioff)                                             \
  _Pragma("unroll")                                                          \
  for (int r = 0; r < 16; ++r) {                                             \
    int rowt = (r & 3) + 8 * (r >> 2) + hb * 4;                              \
    float* cp = C + (size_t)(rowBase + (ioff) + rowt) * N_DIM + colBase;     \
    cp[0]  = (float)(accL[r] + bias0);                                       \
    cp[32] = (float)(accR[r] + bias1);                                       \
  }
  CWRITE(acc00, acc01, 0)
  CWRITE(acc10, acc11, 32)
  CWRITE(acc20, acc21, 64)
  CWRITE(acc30, acc31, 96)
}

// ---------------------------------------------------------------------------

extern "C" void kernel_launch(void* const* d_in, const int* in_sizes, int n_in,
                              void* d_out, int out_size, void* d_ws, size_t ws_size,
                              hipStream_t stream)
{
  const float* x    = (const float*)d_in[0];   // [8192, 4096]
  const float* wgt  = (const float*)d_in[1];   // [4096, 4096]
  const float* bias = (const float*)d_in[2];   // [4096]
  float* out = (float*)d_out;                  // [8192, 4096] f32

  int8_t* A8 = (int8_t*)d_ws;                          // 33.5 MB
  int8_t* B8 = A8 + (size_t)M_DIM * K_DIM;             // 16.8 MB

  f32_to_i8_tiled<<<BLKS_A + BLKS_B, 256, 0, stream>>>(
      x, wgt, (int4*)A8, (int4*)B8);
  gemm_i8<<<dim3(N_DIM / 256, M_DIM / 256), 512, 0, stream>>>(A8, B8, bias, out);
}